// Round 5
// baseline (626.556 us; speedup 1.0000x reference)
//
#include <hip/hip_runtime.h>
#include <hip/hip_bf16.h>

#define NN 100000
#define NE 1600000
#define NF 128
#define NH 64
#define NC 16
#define NB1 391    // ceil(NN/256)
#define NBUK 1563  // ceil(NN/64)

__device__ __forceinline__ float us2f(unsigned short u) {
    return __uint_as_float(((unsigned int)u) << 16);
}
__device__ __forceinline__ unsigned short f2us_rn(float f) {
    unsigned int u = __float_as_uint(f);
    return (unsigned short)((u + 0x7FFFu + ((u >> 16) & 1u)) >> 16);
}
__device__ __forceinline__ float ldf(const void* p, size_t i, bool f32) {
    return f32 ? ((const float*)p)[i] : us2f(((const unsigned short*)p)[i]);
}

// ---------------- dtype sniff (validated R2) ----------------
__global__ void k_sniff(const unsigned short* __restrict__ xu, int* __restrict__ mode) {
    __shared__ int cnt;
    if (threadIdx.x == 0) cnt = 0;
    __syncthreads();
    int c = 0;
    for (int i = threadIdx.x; i < 4096; i += 256) {
        unsigned int e = (xu[i] >> 7) & 0xFFu;
        if (e >= 160u) c++;
    }
    atomicAdd(&cnt, c);
    __syncthreads();
    if (threadIdx.x == 0) mode[0] = (cnt >= 16) ? 1 : 0;
}

// ---------------- degrees (4 edges/thread via int4) ----------------
__global__ void k_deg(const int4* __restrict__ src4, const int4* __restrict__ dst4,
                      int* __restrict__ deg_out, int* __restrict__ deg_in) {
    int i = blockIdx.x * blockDim.x + threadIdx.x;
    if (i < NE / 4) {
        int4 s = src4[i], d = dst4[i];
        atomicAdd(&deg_out[s.x], 1); atomicAdd(&deg_out[s.y], 1);
        atomicAdd(&deg_out[s.z], 1); atomicAdd(&deg_out[s.w], 1);
        atomicAdd(&deg_in[d.x], 1);  atomicAdd(&deg_in[d.y], 1);
        atomicAdd(&deg_in[d.z], 1);  atomicAdd(&deg_in[d.w], 1);
    }
}

// ---------------- CSR build: scan of in-degrees ----------------
__global__ void k_scan_a(const int* __restrict__ deg_in, int* __restrict__ bsum) {
    __shared__ int s[256];
    int i = blockIdx.x * 256 + threadIdx.x;
    s[threadIdx.x] = (i < NN) ? deg_in[i] : 0;
    __syncthreads();
    for (int off = 128; off > 0; off >>= 1) {
        if (threadIdx.x < off) s[threadIdx.x] += s[threadIdx.x + off];
        __syncthreads();
    }
    if (threadIdx.x == 0) bsum[blockIdx.x] = s[0];
}

__global__ void k_scan_b(const int* __restrict__ bsum, int* __restrict__ boff) {
    __shared__ int s[512];
    int t = threadIdx.x;
    s[t] = (t < NB1) ? bsum[t] : 0;
    __syncthreads();
    for (int off = 1; off < 512; off <<= 1) {
        int v = (t >= off) ? s[t - off] : 0;
        __syncthreads();
        s[t] += v;
        __syncthreads();
    }
    if (t < NB1) boff[t] = (t == 0) ? 0 : s[t - 1];
}

// per-block scan -> row_off (+ bucket cursors, fallback cursors, norms)
__global__ void k_scan_c(const int* __restrict__ deg_in, const int* __restrict__ deg_out,
                         const int* __restrict__ boff, int* __restrict__ row_off,
                         int* __restrict__ cursor, int* __restrict__ bcur,
                         float* __restrict__ nsrc, float* __restrict__ ndst) {
    __shared__ int s[256];
    int t = threadIdx.x;
    int i = blockIdx.x * 256 + t;
    int d = (i < NN) ? deg_in[i] : 0;
    s[t] = d;
    __syncthreads();
    for (int off = 1; off < 256; off <<= 1) {
        int v = (t >= off) ? s[t - off] : 0;
        __syncthreads();
        s[t] += v;
        __syncthreads();
    }
    int excl = s[t] - d + boff[blockIdx.x];
    if (i < NN) {
        row_off[i] = excl;
        cursor[i]  = excl;
        if ((i & 63) == 0) bcur[i >> 6] = excl;
        ndst[i] = rsqrtf(fmaxf((float)d, 1.0f));
        nsrc[i] = rsqrtf(fmaxf((float)deg_out[i], 1.0f));
        if (i == NN - 1) row_off[NN] = excl + d;
    }
}

// ---------------- fallback: direct scatter (R3 path) ----------------
__global__ void k_scatter(const int* __restrict__ src, const int* __restrict__ dst,
                          int* __restrict__ cursor, int* __restrict__ srcs_sorted) {
    int e = blockIdx.x * blockDim.x + threadIdx.x;
    if (e < NE) {
        int p = atomicAdd(&cursor[dst[e]], 1);
        srcs_sorted[p] = src[e];
    }
}

// ---------------- fast CSR pass B: bucket append (dense writes) ----------------
// bucket b = dst>>6 owns contiguous region [row_off[64b], row_off[64b+64]).
// packed word = (src << 6) | (dst & 63)  (17+6 = 23 bits).
__global__ void k_bucketB(const int4* __restrict__ src4, const int4* __restrict__ dst4,
                          int* __restrict__ bcur, unsigned int* __restrict__ packed) {
    int i = blockIdx.x * blockDim.x + threadIdx.x;
    if (i < NE / 4) {
        int4 s = src4[i], d = dst4[i];
        int p0 = atomicAdd(&bcur[d.x >> 6], 1);
        int p1 = atomicAdd(&bcur[d.y >> 6], 1);
        int p2 = atomicAdd(&bcur[d.z >> 6], 1);
        int p3 = atomicAdd(&bcur[d.w >> 6], 1);
        packed[p0] = ((unsigned)s.x << 6) | (unsigned)(d.x & 63);
        packed[p1] = ((unsigned)s.y << 6) | (unsigned)(d.y & 63);
        packed[p2] = ((unsigned)s.z << 6) | (unsigned)(d.z & 63);
        packed[p3] = ((unsigned)s.w << 6) | (unsigned)(d.w & 63);
    }
}

// ---------------- fast CSR pass C: within-bucket scatter via LDS cursors ----------------
__global__ __launch_bounds__(256) void k_bucketC(const int* __restrict__ row_off,
                                                 const unsigned int* __restrict__ packed,
                                                 int* __restrict__ srcs_sorted) {
    __shared__ int lcur[64];
    const int b = blockIdx.x;
    const int n0 = b << 6;
    const int n1 = (n0 + 64 < NN) ? n0 + 64 : NN;
    if (threadIdx.x < 64) {
        int n = n0 + threadIdx.x;
        lcur[threadIdx.x] = (n < NN) ? row_off[n] : 0;
    }
    __syncthreads();
    const int beg = row_off[n0], end = row_off[n1];
    for (int i = beg + threadIdx.x; i < end; i += 256) {
        unsigned v = packed[i];
        int p = atomicAdd(&lcur[v & 63u], 1);
        srcs_sorted[p] = (int)(v >> 6);
    }
}

// ---------------- layer 1 GEMM: h1 = bf16((x @ W1) * nsrc) ----------------
__global__ __launch_bounds__(256) void k_gemm1(
    const void* __restrict__ x, const void* __restrict__ W1,
    const float* __restrict__ nsrc, unsigned short* __restrict__ h1,
    const int* __restrict__ mode)
{
    __shared__ float Ws[NF][NH];     // 32 KB
    __shared__ float xs[4][4][NF];   // 8 KB
    const bool f32 = (mode[0] != 0);
    const int tid = threadIdx.x;
    for (int i = tid; i < NF * NH; i += 256) Ws[i / NH][i % NH] = ldf(W1, i, f32);
    __syncthreads();

    const int wave = tid >> 6, lane = tid & 63;
    const int r  = lane >> 4;
    const int k0 = (lane & 15) * 8;

    for (int g = blockIdx.x; g < NN / 16; g += gridDim.x) {
        const int base = g * 16 + wave * 4;
        __syncthreads();
        if (f32) {
            const float4* xp = (const float4*)((const float*)x + (size_t)base * NF);
            float4 v0 = xp[lane * 2], v1 = xp[lane * 2 + 1];
            float* dp = &xs[wave][r][k0];
            dp[0]=v0.x; dp[1]=v0.y; dp[2]=v0.z; dp[3]=v0.w;
            dp[4]=v1.x; dp[5]=v1.y; dp[6]=v1.z; dp[7]=v1.w;
        } else {
            const uint4* xp = (const uint4*)((const unsigned short*)x + (size_t)base * NF);
            uint4 v = xp[lane];
            unsigned short us[8];
            *(uint4*)us = v;
            float* dp = &xs[wave][r][k0];
            #pragma unroll
            for (int j = 0; j < 8; ++j) dp[j] = us2f(us[j]);
        }
        __syncthreads();

        float a0 = 0.f, a1 = 0.f, a2 = 0.f, a3 = 0.f;
        #pragma unroll 4
        for (int k = 0; k < NF; k += 4) {
            float4 x0 = *(const float4*)&xs[wave][0][k];
            float4 x1 = *(const float4*)&xs[wave][1][k];
            float4 x2 = *(const float4*)&xs[wave][2][k];
            float4 x3 = *(const float4*)&xs[wave][3][k];
            float w0 = Ws[k][lane], w1 = Ws[k+1][lane];
            float w2 = Ws[k+2][lane], w3 = Ws[k+3][lane];
            a0 = fmaf(x0.x,w0,fmaf(x0.y,w1,fmaf(x0.z,w2,fmaf(x0.w,w3,a0))));
            a1 = fmaf(x1.x,w0,fmaf(x1.y,w1,fmaf(x1.z,w2,fmaf(x1.w,w3,a1))));
            a2 = fmaf(x2.x,w0,fmaf(x2.y,w1,fmaf(x2.z,w2,fmaf(x2.w,w3,a2))));
            a3 = fmaf(x3.x,w0,fmaf(x3.y,w1,fmaf(x3.z,w2,fmaf(x3.w,w3,a3))));
        }
        h1[(size_t)(base+0)*NH+lane] = f2us_rn(a0 * nsrc[base+0]);
        h1[(size_t)(base+1)*NH+lane] = f2us_rn(a1 * nsrc[base+1]);
        h1[(size_t)(base+2)*NH+lane] = f2us_rn(a2 * nsrc[base+2]);
        h1[(size_t)(base+3)*NH+lane] = f2us_rn(a3 * nsrc[base+3]);
    }
}

// ---------------- fused layer-1 aggregation + relu + W2 GEMM ----------------
__global__ __launch_bounds__(256) void k_agg1csr(
    const int* __restrict__ row_off, const int* __restrict__ srcs,
    const unsigned short* __restrict__ h1, const float* __restrict__ ndst,
    const float* __restrict__ nsrc, const void* __restrict__ b1,
    const void* __restrict__ W2, const int* __restrict__ mode,
    unsigned short* __restrict__ h2)
{
    const bool f32 = (mode[0] != 0);
    const int lane = threadIdx.x & 63;
    const int q  = lane >> 4;    // edge slot / column subset
    const int li = lane & 15;    // feature quad: feats 4li..4li+3

    const float bias0 = ldf(b1, 4*li+0, f32), bias1 = ldf(b1, 4*li+1, f32);
    const float bias2 = ldf(b1, 4*li+2, f32), bias3 = ldf(b1, 4*li+3, f32);
    float w2[4][4];
    #pragma unroll
    for (int j = 0; j < 4; ++j)
        #pragma unroll
        for (int m = 0; m < 4; ++m)
            w2[j][m] = ldf(W2, (size_t)(4*li+j)*NC + (q + 4*m), f32);

    const int wid = (blockIdx.x * blockDim.x + threadIdx.x) >> 6;
    const int nw  = (gridDim.x * blockDim.x) >> 6;

    for (int row = wid; row < NN; row += nw) {
        const int beg = row_off[row], end = row_off[row + 1];
        float ax = 0.f, ay = 0.f, az = 0.f, aw = 0.f;
        float bx = 0.f, by = 0.f, bz = 0.f, bw = 0.f;
        int i = beg + q;
        int s0 = (i     < end) ? srcs[i]     : 0;
        int s1 = (i + 4 < end) ? srcs[i + 4] : 0;
        while (i + 4 < end) {
            uint2 v0 = *(const uint2*)(h1 + (size_t)s0 * NH + 4*li);
            uint2 v1 = *(const uint2*)(h1 + (size_t)s1 * NH + 4*li);
            const int inext = i + 8;
            s0 = (inext     < end) ? srcs[inext]     : 0;
            s1 = (inext + 4 < end) ? srcs[inext + 4] : 0;
            ax += us2f((unsigned short)(v0.x & 0xFFFF));
            ay += us2f((unsigned short)(v0.x >> 16));
            az += us2f((unsigned short)(v0.y & 0xFFFF));
            aw += us2f((unsigned short)(v0.y >> 16));
            bx += us2f((unsigned short)(v1.x & 0xFFFF));
            by += us2f((unsigned short)(v1.x >> 16));
            bz += us2f((unsigned short)(v1.y & 0xFFFF));
            bw += us2f((unsigned short)(v1.y >> 16));
            i = inext;
        }
        if (i < end) {
            uint2 v0 = *(const uint2*)(h1 + (size_t)s0 * NH + 4*li);
            ax += us2f((unsigned short)(v0.x & 0xFFFF));
            ay += us2f((unsigned short)(v0.x >> 16));
            az += us2f((unsigned short)(v0.y & 0xFFFF));
            aw += us2f((unsigned short)(v0.y >> 16));
        }
        ax += bx; ay += by; az += bz; aw += bw;
        ax += __shfl_xor(ax, 16); ay += __shfl_xor(ay, 16);
        az += __shfl_xor(az, 16); aw += __shfl_xor(aw, 16);
        ax += __shfl_xor(ax, 32); ay += __shfl_xor(ay, 32);
        az += __shfl_xor(az, 32); aw += __shfl_xor(aw, 32);

        const float nd = ndst[row];
        const float t0 = fmaxf(fmaf(ax, nd, bias0), 0.f);
        const float t1 = fmaxf(fmaf(ay, nd, bias1), 0.f);
        const float t2 = fmaxf(fmaf(az, nd, bias2), 0.f);
        const float t3 = fmaxf(fmaf(aw, nd, bias3), 0.f);

        float p0 = fmaf(t0,w2[0][0],fmaf(t1,w2[1][0],fmaf(t2,w2[2][0],t3*w2[3][0])));
        float p1 = fmaf(t0,w2[0][1],fmaf(t1,w2[1][1],fmaf(t2,w2[2][1],t3*w2[3][1])));
        float p2 = fmaf(t0,w2[0][2],fmaf(t1,w2[1][2],fmaf(t2,w2[2][2],t3*w2[3][2])));
        float p3 = fmaf(t0,w2[0][3],fmaf(t1,w2[1][3],fmaf(t2,w2[2][3],t3*w2[3][3])));
        #pragma unroll
        for (int off = 1; off <= 8; off <<= 1) {
            p0 += __shfl_xor(p0, off);
            p1 += __shfl_xor(p1, off);
            p2 += __shfl_xor(p2, off);
            p3 += __shfl_xor(p3, off);
        }
        if (li < 4) {
            float v = (li == 0) ? p0 : (li == 1) ? p1 : (li == 2) ? p2 : p3;
            h2[(size_t)row * NC + q + 4*li] = f2us_rn(v * nsrc[row]);
        }
    }
}

// ---------------- fused layer-2 aggregation + bias + log_softmax ----------------
__global__ __launch_bounds__(256) void k_out(
    const int* __restrict__ row_off, const int* __restrict__ srcs,
    const unsigned short* __restrict__ h2, const float* __restrict__ ndst,
    const void* __restrict__ b2, const int* __restrict__ mode,
    void* __restrict__ out)
{
    const bool f32 = (mode[0] != 0);
    const int lane = threadIdx.x & 63;
    const int q  = lane >> 4;
    const int li = lane & 15;
    const float b2v = ldf(b2, li, f32);

    const int wid = (blockIdx.x * blockDim.x + threadIdx.x) >> 6;
    const int nw  = (gridDim.x * blockDim.x) >> 6;

    for (int r = wid; r < NN; r += nw) {
        const int beg = row_off[r], end = row_off[r + 1];
        float a = 0.f, b = 0.f;
        int i = beg + q;
        int s0 = (i     < end) ? srcs[i]     : 0;
        int s1 = (i + 4 < end) ? srcs[i + 4] : 0;
        while (i + 4 < end) {
            float va = us2f(h2[(size_t)s0 * NC + li]);
            float vb = us2f(h2[(size_t)s1 * NC + li]);
            const int inext = i + 8;
            s0 = (inext     < end) ? srcs[inext]     : 0;
            s1 = (inext + 4 < end) ? srcs[inext + 4] : 0;
            a += va; b += vb;
            i = inext;
        }
        if (i < end) a += us2f(h2[(size_t)s0 * NC + li]);
        a += b;
        a += __shfl_xor(a, 16);
        a += __shfl_xor(a, 32);
        float v = fmaf(a, ndst[r], b2v);
        float m = v;
        #pragma unroll
        for (int off = 8; off >= 1; off >>= 1) m = fmaxf(m, __shfl_xor(m, off));
        float ex = __expf(v - m);
        float sm = ex;
        #pragma unroll
        for (int off = 8; off >= 1; off >>= 1) sm += __shfl_xor(sm, off);
        float res = v - m - __logf(sm);
        if (lane < 16) {
            if (f32) ((float*)out)[(size_t)r * NC + li] = res;
            else ((__hip_bfloat16*)out)[(size_t)r * NC + li] = __float2bfloat16(res);
        }
    }
}

extern "C" void kernel_launch(void* const* d_in, const int* in_sizes, int n_in,
                              void* d_out, int out_size, void* d_ws, size_t ws_size,
                              hipStream_t stream) {
    const void* x  = d_in[0];
    const int* src = (const int*)d_in[1];
    const int* dst = (const int*)d_in[2];
    const void* W1 = d_in[3];
    const void* b1 = d_in[4];
    const void* W2 = d_in[5];
    const void* b2 = d_in[6];

    // ---- workspace layout ----
    char* ws = (char*)d_ws;
    const size_t O_MODE = 0;                     // 1 KB
    const size_t O_DEG  = 1024;                  // 800000
    const size_t O_NSRC = O_DEG  + 800000;
    const size_t O_NDST = O_NSRC + 400000;
    const size_t O_ROW  = O_NDST + 400000;       // (NN+1)*4 padded
    const size_t O_CUR  = O_ROW  + 400128;       // fallback per-node cursors
    const size_t O_BCUR = O_CUR  + 400128;       // NBUK ints -> pad 6400
    const size_t O_BS   = O_BCUR + 6400;         // bsum 2048 + boff 2048
    const size_t O_SRCS = O_BS   + 4096;         // NE*4
    const size_t O_H2   = O_SRCS + 6400000;      // NN*NC*2 bf16
    const size_t O_H1   = O_H2   + 3200000;      // NN*NH*2 bf16
    const size_t O_PACK = O_H1   + 12800000;     // NE*4 (fast CSR only)
    const size_t NEED_FAST = O_PACK + 6400000;   // ~31.2 MB
    const bool fast_csr = ws_size >= NEED_FAST;

    int*   mode    = (int*)(ws + O_MODE);
    int*   deg_out = (int*)(ws + O_DEG);
    int*   deg_in  = deg_out + NN;
    float* nsrc    = (float*)(ws + O_NSRC);
    float* ndst    = (float*)(ws + O_NDST);
    int*   row_off = (int*)(ws + O_ROW);
    int*   cursor  = (int*)(ws + O_CUR);
    int*   bcur    = (int*)(ws + O_BCUR);
    int*   bsum    = (int*)(ws + O_BS);
    int*   boff    = (int*)(ws + O_BS + 2048);
    int*   srcs_s  = (int*)(ws + O_SRCS);
    unsigned short* h2 = (unsigned short*)(ws + O_H2);
    unsigned short* h1 = (unsigned short*)(ws + O_H1);
    unsigned int* packed = (unsigned int*)(ws + O_PACK);

    k_sniff<<<1, 256, 0, stream>>>((const unsigned short*)x, mode);
    hipMemsetAsync(deg_out, 0, 2 * (size_t)NN * sizeof(int), stream);
    k_deg<<<(NE / 4 + 255) / 256, 256, 0, stream>>>((const int4*)src, (const int4*)dst, deg_out, deg_in);
    k_scan_a<<<NB1, 256, 0, stream>>>(deg_in, bsum);
    k_scan_b<<<1, 512, 0, stream>>>(bsum, boff);
    k_scan_c<<<NB1, 256, 0, stream>>>(deg_in, deg_out, boff, row_off, cursor, bcur, nsrc, ndst);
    if (fast_csr) {
        k_bucketB<<<(NE / 4 + 255) / 256, 256, 0, stream>>>((const int4*)src, (const int4*)dst, bcur, packed);
        k_bucketC<<<NBUK, 256, 0, stream>>>(row_off, packed, srcs_s);
    } else {
        k_scatter<<<(NE + 255) / 256, 256, 0, stream>>>(src, dst, cursor, srcs_s);
    }
    k_gemm1<<<2048, 256, 0, stream>>>(x, W1, nsrc, h1, mode);
    k_agg1csr<<<2048, 256, 0, stream>>>(row_off, srcs_s, h1, ndst, nsrc, b1, W2, mode, h2);
    k_out<<<2048, 256, 0, stream>>>(row_off, srcs_s, h2, ndst, b2, mode, d_out);
}

// Round 6
// 418.450 us; speedup vs baseline: 1.4973x; 1.4973x over previous
//
#include <hip/hip_runtime.h>
#include <hip/hip_bf16.h>

#define NN 100000
#define NE 1600000
#define NF 128
#define NH 64
#define NC 16
#define NB1 391    // ceil(NN/256)
#define GBIN 256   // binning workgroups
#define CHUNK 6250 // NE/GBIN
#define BBUK 196   // ceil(NN/512) coarse buckets of 512 nodes
#define NCB 196    // scan blocks for counts: BBUK*GBIN/256

__device__ __forceinline__ float us2f(unsigned short u) {
    return __uint_as_float(((unsigned int)u) << 16);
}
__device__ __forceinline__ unsigned short f2us_rn(float f) {
    unsigned int u = __float_as_uint(f);
    return (unsigned short)((u + 0x7FFFu + ((u >> 16) & 1u)) >> 16);
}
__device__ __forceinline__ float ldf(const void* p, size_t i, bool f32) {
    return f32 ? ((const float*)p)[i] : us2f(((const unsigned short*)p)[i]);
}

// ---------------- dtype sniff (validated R2) ----------------
__global__ void k_sniff(const unsigned short* __restrict__ xu, int* __restrict__ mode) {
    __shared__ int cnt;
    if (threadIdx.x == 0) cnt = 0;
    __syncthreads();
    int c = 0;
    for (int i = threadIdx.x; i < 4096; i += 256) {
        unsigned int e = (xu[i] >> 7) & 0xFFu;
        if (e >= 160u) c++;
    }
    atomicAdd(&cnt, c);
    __syncthreads();
    if (threadIdx.x == 0) mode[0] = (cnt >= 16) ? 1 : 0;
}

// ---------------- degrees (4 edges/thread via int4) ----------------
__global__ void k_deg(const int4* __restrict__ src4, const int4* __restrict__ dst4,
                      int* __restrict__ deg_out, int* __restrict__ deg_in) {
    int i = blockIdx.x * blockDim.x + threadIdx.x;
    if (i < NE / 4) {
        int4 s = src4[i], d = dst4[i];
        atomicAdd(&deg_out[s.x], 1); atomicAdd(&deg_out[s.y], 1);
        atomicAdd(&deg_out[s.z], 1); atomicAdd(&deg_out[s.w], 1);
        atomicAdd(&deg_in[d.x], 1);  atomicAdd(&deg_in[d.y], 1);
        atomicAdd(&deg_in[d.z], 1);  atomicAdd(&deg_in[d.w], 1);
    }
}

// ---------------- node-level scan -> row_off, cursors, norms ----------------
__global__ void k_scan_a(const int* __restrict__ deg_in, int* __restrict__ bsum) {
    __shared__ int s[256];
    int i = blockIdx.x * 256 + threadIdx.x;
    s[threadIdx.x] = (i < NN) ? deg_in[i] : 0;
    __syncthreads();
    for (int off = 128; off > 0; off >>= 1) {
        if (threadIdx.x < off) s[threadIdx.x] += s[threadIdx.x + off];
        __syncthreads();
    }
    if (threadIdx.x == 0) bsum[blockIdx.x] = s[0];
}

__global__ void k_scan_b(const int* __restrict__ bsum, int* __restrict__ boff) {
    __shared__ int s[512];
    int t = threadIdx.x;
    s[t] = (t < NB1) ? bsum[t] : 0;
    __syncthreads();
    for (int off = 1; off < 512; off <<= 1) {
        int v = (t >= off) ? s[t - off] : 0;
        __syncthreads();
        s[t] += v;
        __syncthreads();
    }
    if (t < NB1) boff[t] = (t == 0) ? 0 : s[t - 1];
}

__global__ void k_scan_c(const int* __restrict__ deg_in, const int* __restrict__ deg_out,
                         const int* __restrict__ boff, int* __restrict__ row_off,
                         int* __restrict__ cursor, float* __restrict__ nsrc,
                         float* __restrict__ ndst) {
    __shared__ int s[256];
    int t = threadIdx.x;
    int i = blockIdx.x * 256 + t;
    int d = (i < NN) ? deg_in[i] : 0;
    s[t] = d;
    __syncthreads();
    for (int off = 1; off < 256; off <<= 1) {
        int v = (t >= off) ? s[t - off] : 0;
        __syncthreads();
        s[t] += v;
        __syncthreads();
    }
    int excl = s[t] - d + boff[blockIdx.x];
    if (i < NN) {
        row_off[i] = excl;
        cursor[i]  = excl;
        ndst[i] = rsqrtf(fmaxf((float)d, 1.0f));
        nsrc[i] = rsqrtf(fmaxf((float)deg_out[i], 1.0f));
        if (i == NN - 1) row_off[NN] = excl + d;
    }
}

// ---------------- fallback: direct scatter (R3/R4 path, 126 us) ----------------
__global__ void k_scatter(const int* __restrict__ src, const int* __restrict__ dst,
                          int* __restrict__ cursor, int* __restrict__ srcs_sorted) {
    int e = blockIdx.x * blockDim.x + threadIdx.x;
    if (e < NE) {
        int p = atomicAdd(&cursor[dst[e]], 1);
        srcs_sorted[p] = src[e];
    }
}

// ---------------- fast CSR 1/4: per-(bucket,group) histogram ----------------
__global__ __launch_bounds__(256) void k_hist(const int* __restrict__ dst,
                                              int* __restrict__ counts) {
    __shared__ int hist[BBUK];
    for (int i = threadIdx.x; i < BBUK; i += 256) hist[i] = 0;
    __syncthreads();
    const int g = blockIdx.x;
    const int e0 = g * CHUNK;
    for (int i = threadIdx.x; i < CHUNK; i += 256)
        atomicAdd(&hist[dst[e0 + i] >> 9], 1);
    __syncthreads();
    for (int i = threadIdx.x; i < BBUK; i += 256)
        counts[i * GBIN + g] = hist[i];
}

// ---------------- fast CSR 2/4: exclusive scan of counts (50176 ints) ----------------
__global__ void k_cs_a(const int* __restrict__ counts, int* __restrict__ csum) {
    __shared__ int s[256];
    int i = blockIdx.x * 256 + threadIdx.x;
    s[threadIdx.x] = counts[i];
    __syncthreads();
    for (int off = 128; off > 0; off >>= 1) {
        if (threadIdx.x < off) s[threadIdx.x] += s[threadIdx.x + off];
        __syncthreads();
    }
    if (threadIdx.x == 0) csum[blockIdx.x] = s[0];
}

__global__ void k_cs_b(const int* __restrict__ csum, int* __restrict__ coff) {
    __shared__ int s[256];
    int t = threadIdx.x;
    s[t] = (t < NCB) ? csum[t] : 0;
    __syncthreads();
    for (int off = 1; off < 256; off <<= 1) {
        int v = (t >= off) ? s[t - off] : 0;
        __syncthreads();
        s[t] += v;
        __syncthreads();
    }
    if (t < NCB) coff[t] = (t == 0) ? 0 : s[t - 1];
}

__global__ void k_cs_c(int* __restrict__ counts, const int* __restrict__ coff) {
    __shared__ int s[256];
    int t = threadIdx.x;
    int i = blockIdx.x * 256 + t;
    int v = counts[i];
    s[t] = v;
    __syncthreads();
    for (int off = 1; off < 256; off <<= 1) {
        int u = (t >= off) ? s[t - off] : 0;
        __syncthreads();
        s[t] += u;
        __syncthreads();
    }
    counts[i] = s[t] - v + coff[blockIdx.x];
}

// ---------------- fast CSR 3/4: private-slice binning scatter ----------------
// group g writes each bucket's slice [counts[b][g], counts[b][g+1]) -- slices
// are workgroup-private, so lines fill fast in one XCD's L2 (single writeback).
__global__ __launch_bounds__(256) void k_binscatter(const int* __restrict__ src,
                                                    const int* __restrict__ dst,
                                                    const int* __restrict__ counts,
                                                    unsigned int* __restrict__ packed) {
    __shared__ int cur[BBUK];
    const int g = blockIdx.x;
    for (int i = threadIdx.x; i < BBUK; i += 256) cur[i] = counts[i * GBIN + g];
    __syncthreads();
    const int e0 = g * CHUNK;
    for (int i = threadIdx.x; i < CHUNK; i += 256) {
        int s = src[e0 + i], d = dst[e0 + i];
        int p = atomicAdd(&cur[d >> 9], 1);
        packed[p] = ((unsigned)s << 9) | (unsigned)(d & 511);
    }
}

// ---------------- fast CSR 4/4: within-bucket scatter via LDS cursors ----------------
__global__ __launch_bounds__(256) void k_bucketC512(const int* __restrict__ row_off,
                                                    const unsigned int* __restrict__ packed,
                                                    int* __restrict__ srcs_sorted) {
    __shared__ int lcur[512];
    const int n0 = blockIdx.x << 9;
    const int nlim = (NN - n0 < 512) ? (NN - n0) : 512;
    for (int j = threadIdx.x; j < 512; j += 256)
        lcur[j] = (j < nlim) ? row_off[n0 + j] : 0;
    __syncthreads();
    const int beg = row_off[n0];
    const int end = row_off[n0 + nlim];
    for (int i = beg + threadIdx.x; i < end; i += 256) {
        unsigned v = packed[i];
        int p = atomicAdd(&lcur[v & 511u], 1);
        srcs_sorted[p] = (int)(v >> 9);
    }
}

// ---------------- layer 1 GEMM: h1 = bf16((x @ W1) * nsrc) ----------------
__global__ __launch_bounds__(256) void k_gemm1(
    const void* __restrict__ x, const void* __restrict__ W1,
    const float* __restrict__ nsrc, unsigned short* __restrict__ h1,
    const int* __restrict__ mode)
{
    __shared__ float Ws[NF][NH];     // 32 KB
    __shared__ float xs[4][4][NF];   // 8 KB
    const bool f32 = (mode[0] != 0);
    const int tid = threadIdx.x;
    for (int i = tid; i < NF * NH; i += 256) Ws[i / NH][i % NH] = ldf(W1, i, f32);
    __syncthreads();

    const int wave = tid >> 6, lane = tid & 63;
    const int r  = lane >> 4;
    const int k0 = (lane & 15) * 8;

    for (int g = blockIdx.x; g < NN / 16; g += gridDim.x) {
        const int base = g * 16 + wave * 4;
        __syncthreads();
        if (f32) {
            const float4* xp = (const float4*)((const float*)x + (size_t)base * NF);
            float4 v0 = xp[lane * 2], v1 = xp[lane * 2 + 1];
            float* dp = &xs[wave][r][k0];
            dp[0]=v0.x; dp[1]=v0.y; dp[2]=v0.z; dp[3]=v0.w;
            dp[4]=v1.x; dp[5]=v1.y; dp[6]=v1.z; dp[7]=v1.w;
        } else {
            const uint4* xp = (const uint4*)((const unsigned short*)x + (size_t)base * NF);
            uint4 v = xp[lane];
            unsigned short us[8];
            *(uint4*)us = v;
            float* dp = &xs[wave][r][k0];
            #pragma unroll
            for (int j = 0; j < 8; ++j) dp[j] = us2f(us[j]);
        }
        __syncthreads();

        float a0 = 0.f, a1 = 0.f, a2 = 0.f, a3 = 0.f;
        #pragma unroll 4
        for (int k = 0; k < NF; k += 4) {
            float4 x0 = *(const float4*)&xs[wave][0][k];
            float4 x1 = *(const float4*)&xs[wave][1][k];
            float4 x2 = *(const float4*)&xs[wave][2][k];
            float4 x3 = *(const float4*)&xs[wave][3][k];
            float w0 = Ws[k][lane], w1 = Ws[k+1][lane];
            float w2 = Ws[k+2][lane], w3 = Ws[k+3][lane];
            a0 = fmaf(x0.x,w0,fmaf(x0.y,w1,fmaf(x0.z,w2,fmaf(x0.w,w3,a0))));
            a1 = fmaf(x1.x,w0,fmaf(x1.y,w1,fmaf(x1.z,w2,fmaf(x1.w,w3,a1))));
            a2 = fmaf(x2.x,w0,fmaf(x2.y,w1,fmaf(x2.z,w2,fmaf(x2.w,w3,a2))));
            a3 = fmaf(x3.x,w0,fmaf(x3.y,w1,fmaf(x3.z,w2,fmaf(x3.w,w3,a3))));
        }
        h1[(size_t)(base+0)*NH+lane] = f2us_rn(a0 * nsrc[base+0]);
        h1[(size_t)(base+1)*NH+lane] = f2us_rn(a1 * nsrc[base+1]);
        h1[(size_t)(base+2)*NH+lane] = f2us_rn(a2 * nsrc[base+2]);
        h1[(size_t)(base+3)*NH+lane] = f2us_rn(a3 * nsrc[base+3]);
    }
}

// ---------------- fused layer-1 aggregation + relu + W2 GEMM ----------------
__global__ __launch_bounds__(256) void k_agg1csr(
    const int* __restrict__ row_off, const int* __restrict__ srcs,
    const unsigned short* __restrict__ h1, const float* __restrict__ ndst,
    const float* __restrict__ nsrc, const void* __restrict__ b1,
    const void* __restrict__ W2, const int* __restrict__ mode,
    unsigned short* __restrict__ h2)
{
    const bool f32 = (mode[0] != 0);
    const int lane = threadIdx.x & 63;
    const int q  = lane >> 4;    // edge slot / column subset
    const int li = lane & 15;    // feature quad: feats 4li..4li+3

    const float bias0 = ldf(b1, 4*li+0, f32), bias1 = ldf(b1, 4*li+1, f32);
    const float bias2 = ldf(b1, 4*li+2, f32), bias3 = ldf(b1, 4*li+3, f32);
    float w2[4][4];
    #pragma unroll
    for (int j = 0; j < 4; ++j)
        #pragma unroll
        for (int m = 0; m < 4; ++m)
            w2[j][m] = ldf(W2, (size_t)(4*li+j)*NC + (q + 4*m), f32);

    const int wid = (blockIdx.x * blockDim.x + threadIdx.x) >> 6;
    const int nw  = (gridDim.x * blockDim.x) >> 6;

    for (int row = wid; row < NN; row += nw) {
        const int beg = row_off[row], end = row_off[row + 1];
        float ax = 0.f, ay = 0.f, az = 0.f, aw = 0.f;
        float bx = 0.f, by = 0.f, bz = 0.f, bw = 0.f;
        int i = beg + q;
        int s0 = (i     < end) ? srcs[i]     : 0;
        int s1 = (i + 4 < end) ? srcs[i + 4] : 0;
        while (i + 4 < end) {
            uint2 v0 = *(const uint2*)(h1 + (size_t)s0 * NH + 4*li);
            uint2 v1 = *(const uint2*)(h1 + (size_t)s1 * NH + 4*li);
            const int inext = i + 8;
            s0 = (inext     < end) ? srcs[inext]     : 0;
            s1 = (inext + 4 < end) ? srcs[inext + 4] : 0;
            ax += us2f((unsigned short)(v0.x & 0xFFFF));
            ay += us2f((unsigned short)(v0.x >> 16));
            az += us2f((unsigned short)(v0.y & 0xFFFF));
            aw += us2f((unsigned short)(v0.y >> 16));
            bx += us2f((unsigned short)(v1.x & 0xFFFF));
            by += us2f((unsigned short)(v1.x >> 16));
            bz += us2f((unsigned short)(v1.y & 0xFFFF));
            bw += us2f((unsigned short)(v1.y >> 16));
            i = inext;
        }
        if (i < end) {
            uint2 v0 = *(const uint2*)(h1 + (size_t)s0 * NH + 4*li);
            ax += us2f((unsigned short)(v0.x & 0xFFFF));
            ay += us2f((unsigned short)(v0.x >> 16));
            az += us2f((unsigned short)(v0.y & 0xFFFF));
            aw += us2f((unsigned short)(v0.y >> 16));
        }
        ax += bx; ay += by; az += bz; aw += bw;
        ax += __shfl_xor(ax, 16); ay += __shfl_xor(ay, 16);
        az += __shfl_xor(az, 16); aw += __shfl_xor(aw, 16);
        ax += __shfl_xor(ax, 32); ay += __shfl_xor(ay, 32);
        az += __shfl_xor(az, 32); aw += __shfl_xor(aw, 32);

        const float nd = ndst[row];
        const float t0 = fmaxf(fmaf(ax, nd, bias0), 0.f);
        const float t1 = fmaxf(fmaf(ay, nd, bias1), 0.f);
        const float t2 = fmaxf(fmaf(az, nd, bias2), 0.f);
        const float t3 = fmaxf(fmaf(aw, nd, bias3), 0.f);

        float p0 = fmaf(t0,w2[0][0],fmaf(t1,w2[1][0],fmaf(t2,w2[2][0],t3*w2[3][0])));
        float p1 = fmaf(t0,w2[0][1],fmaf(t1,w2[1][1],fmaf(t2,w2[2][1],t3*w2[3][1])));
        float p2 = fmaf(t0,w2[0][2],fmaf(t1,w2[1][2],fmaf(t2,w2[2][2],t3*w2[3][2])));
        float p3 = fmaf(t0,w2[0][3],fmaf(t1,w2[1][3],fmaf(t2,w2[2][3],t3*w2[3][3])));
        #pragma unroll
        for (int off = 1; off <= 8; off <<= 1) {
            p0 += __shfl_xor(p0, off);
            p1 += __shfl_xor(p1, off);
            p2 += __shfl_xor(p2, off);
            p3 += __shfl_xor(p3, off);
        }
        if (li < 4) {
            float v = (li == 0) ? p0 : (li == 1) ? p1 : (li == 2) ? p2 : p3;
            h2[(size_t)row * NC + q + 4*li] = f2us_rn(v * nsrc[row]);
        }
    }
}

// ---------------- fused layer-2 aggregation + bias + log_softmax ----------------
__global__ __launch_bounds__(256) void k_out(
    const int* __restrict__ row_off, const int* __restrict__ srcs,
    const unsigned short* __restrict__ h2, const float* __restrict__ ndst,
    const void* __restrict__ b2, const int* __restrict__ mode,
    void* __restrict__ out)
{
    const bool f32 = (mode[0] != 0);
    const int lane = threadIdx.x & 63;
    const int q  = lane >> 4;
    const int li = lane & 15;
    const float b2v = ldf(b2, li, f32);

    const int wid = (blockIdx.x * blockDim.x + threadIdx.x) >> 6;
    const int nw  = (gridDim.x * blockDim.x) >> 6;

    for (int r = wid; r < NN; r += nw) {
        const int beg = row_off[r], end = row_off[r + 1];
        float a = 0.f, b = 0.f;
        int i = beg + q;
        int s0 = (i     < end) ? srcs[i]     : 0;
        int s1 = (i + 4 < end) ? srcs[i + 4] : 0;
        while (i + 4 < end) {
            float va = us2f(h2[(size_t)s0 * NC + li]);
            float vb = us2f(h2[(size_t)s1 * NC + li]);
            const int inext = i + 8;
            s0 = (inext     < end) ? srcs[inext]     : 0;
            s1 = (inext + 4 < end) ? srcs[inext + 4] : 0;
            a += va; b += vb;
            i = inext;
        }
        if (i < end) a += us2f(h2[(size_t)s0 * NC + li]);
        a += b;
        a += __shfl_xor(a, 16);
        a += __shfl_xor(a, 32);
        float v = fmaf(a, ndst[r], b2v);
        float m = v;
        #pragma unroll
        for (int off = 8; off >= 1; off >>= 1) m = fmaxf(m, __shfl_xor(m, off));
        float ex = __expf(v - m);
        float sm = ex;
        #pragma unroll
        for (int off = 8; off >= 1; off >>= 1) sm += __shfl_xor(sm, off);
        float res = v - m - __logf(sm);
        if (lane < 16) {
            if (f32) ((float*)out)[(size_t)r * NC + li] = res;
            else ((__hip_bfloat16*)out)[(size_t)r * NC + li] = __float2bfloat16(res);
        }
    }
}

extern "C" void kernel_launch(void* const* d_in, const int* in_sizes, int n_in,
                              void* d_out, int out_size, void* d_ws, size_t ws_size,
                              hipStream_t stream) {
    const void* x  = d_in[0];
    const int* src = (const int*)d_in[1];
    const int* dst = (const int*)d_in[2];
    const void* W1 = d_in[3];
    const void* b1 = d_in[4];
    const void* W2 = d_in[5];
    const void* b2 = d_in[6];

    // ---- workspace layout ----
    char* ws = (char*)d_ws;
    const size_t O_MODE = 0;                     // 1 KB
    const size_t O_DEG  = 1024;                  // 800000
    const size_t O_NSRC = O_DEG  + 800000;
    const size_t O_NDST = O_NSRC + 400000;
    const size_t O_ROW  = O_NDST + 400000;       // (NN+1)*4 padded
    const size_t O_CUR  = O_ROW  + 400128;       // fallback per-node cursors
    const size_t O_CNT  = O_CUR  + 400128;       // counts BBUK*GBIN*4 = 200704
    const size_t O_CS   = O_CNT  + 200704;       // csum 1024 + coff 1024
    const size_t O_BS   = O_CS   + 2048;         // bsum 2048 + boff 2048
    const size_t O_SRCS = O_BS   + 4096;         // NE*4
    const size_t O_H2   = O_SRCS + 6400000;      // NN*NC*2 bf16
    const size_t O_H1   = O_H2   + 3200000;      // NN*NH*2 bf16
    const size_t O_PACK = O_H1   + 12800000;     // NE*4 (fast CSR only)
    const size_t NEED_FAST = O_PACK + 6400000;   // ~31.4 MB
    const bool fast_csr = ws_size >= NEED_FAST;

    int*   mode    = (int*)(ws + O_MODE);
    int*   deg_out = (int*)(ws + O_DEG);
    int*   deg_in  = deg_out + NN;
    float* nsrc    = (float*)(ws + O_NSRC);
    float* ndst    = (float*)(ws + O_NDST);
    int*   row_off = (int*)(ws + O_ROW);
    int*   cursor  = (int*)(ws + O_CUR);
    int*   counts  = (int*)(ws + O_CNT);
    int*   csum    = (int*)(ws + O_CS);
    int*   coff    = (int*)(ws + O_CS + 1024);
    int*   bsum    = (int*)(ws + O_BS);
    int*   boff    = (int*)(ws + O_BS + 2048);
    int*   srcs_s  = (int*)(ws + O_SRCS);
    unsigned short* h2 = (unsigned short*)(ws + O_H2);
    unsigned short* h1 = (unsigned short*)(ws + O_H1);
    unsigned int* packed = (unsigned int*)(ws + O_PACK);

    k_sniff<<<1, 256, 0, stream>>>((const unsigned short*)x, mode);
    hipMemsetAsync(deg_out, 0, 2 * (size_t)NN * sizeof(int), stream);
    k_deg<<<(NE / 4 + 255) / 256, 256, 0, stream>>>((const int4*)src, (const int4*)dst, deg_out, deg_in);
    k_scan_a<<<NB1, 256, 0, stream>>>(deg_in, bsum);
    k_scan_b<<<1, 512, 0, stream>>>(bsum, boff);
    k_scan_c<<<NB1, 256, 0, stream>>>(deg_in, deg_out, boff, row_off, cursor, nsrc, ndst);
    if (fast_csr) {
        k_hist<<<GBIN, 256, 0, stream>>>(dst, counts);
        k_cs_a<<<NCB, 256, 0, stream>>>(counts, csum);
        k_cs_b<<<1, 256, 0, stream>>>(csum, coff);
        k_cs_c<<<NCB, 256, 0, stream>>>(counts, coff);
        k_binscatter<<<GBIN, 256, 0, stream>>>(src, dst, counts, packed);
        k_bucketC512<<<BBUK, 256, 0, stream>>>(row_off, packed, srcs_s);
    } else {
        k_scatter<<<(NE + 255) / 256, 256, 0, stream>>>(src, dst, cursor, srcs_s);
    }
    k_gemm1<<<2048, 256, 0, stream>>>(x, W1, nsrc, h1, mode);
    k_agg1csr<<<2048, 256, 0, stream>>>(row_off, srcs_s, h1, ndst, nsrc, b1, W2, mode, h2);
    k_out<<<2048, 256, 0, stream>>>(row_off, srcs_s, h2, ndst, b2, mode, d_out);
}

// Round 7
// 321.101 us; speedup vs baseline: 1.9513x; 1.3032x over previous
//
#include <hip/hip_runtime.h>
#include <hip/hip_bf16.h>

#define NN 100000
#define NE 1600000
#define NF 128
#define NH 64
#define NC 16
#define NB1 391    // ceil(NN/256)
#define GBIN 256   // binning workgroups
#define CHUNK 6250 // NE/GBIN
#define BBUK 196   // ceil(NN/512) coarse buckets of 512 nodes
#define NCB 196    // 256-blocks per counts array (BBUK*GBIN/256)

__device__ __forceinline__ float us2f(unsigned short u) {
    return __uint_as_float(((unsigned int)u) << 16);
}
__device__ __forceinline__ unsigned short f2us_rn(float f) {
    unsigned int u = __float_as_uint(f);
    return (unsigned short)((u + 0x7FFFu + ((u >> 16) & 1u)) >> 16);
}
__device__ __forceinline__ float ldf(const void* p, size_t i, bool f32) {
    return f32 ? ((const float*)p)[i] : us2f(((const unsigned short*)p)[i]);
}

// ---------------- dtype sniff (validated R2) ----------------
__global__ void k_sniff(const unsigned short* __restrict__ xu, int* __restrict__ mode) {
    __shared__ int cnt;
    if (threadIdx.x == 0) cnt = 0;
    __syncthreads();
    int c = 0;
    for (int i = threadIdx.x; i < 4096; i += 256) {
        unsigned int e = (xu[i] >> 7) & 0xFFu;
        if (e >= 160u) c++;
    }
    atomicAdd(&cnt, c);
    __syncthreads();
    if (threadIdx.x == 0) mode[0] = (cnt >= 16) ? 1 : 0;
}

// ---------------- fallback path kernels (global atomics) ----------------
__global__ void k_deg(const int4* __restrict__ src4, const int4* __restrict__ dst4,
                      int* __restrict__ deg_out, int* __restrict__ deg_in) {
    int i = blockIdx.x * blockDim.x + threadIdx.x;
    if (i < NE / 4) {
        int4 s = src4[i], d = dst4[i];
        atomicAdd(&deg_out[s.x], 1); atomicAdd(&deg_out[s.y], 1);
        atomicAdd(&deg_out[s.z], 1); atomicAdd(&deg_out[s.w], 1);
        atomicAdd(&deg_in[d.x], 1);  atomicAdd(&deg_in[d.y], 1);
        atomicAdd(&deg_in[d.z], 1);  atomicAdd(&deg_in[d.w], 1);
    }
}

__global__ void k_scatter(const int* __restrict__ src, const int* __restrict__ dst,
                          int* __restrict__ cursor, int* __restrict__ srcs_sorted) {
    int e = blockIdx.x * blockDim.x + threadIdx.x;
    if (e < NE) {
        int p = atomicAdd(&cursor[dst[e]], 1);
        srcs_sorted[p] = src[e];
    }
}

// ---------------- fast CSR 1: per-(bucket,group) histograms of dst AND src ----------------
__global__ __launch_bounds__(256) void k_hist2(const int* __restrict__ src,
                                               const int* __restrict__ dst,
                                               int* __restrict__ counts_d,
                                               int* __restrict__ counts_s) {
    __shared__ int hd[BBUK], hs[BBUK];
    for (int i = threadIdx.x; i < BBUK; i += 256) { hd[i] = 0; hs[i] = 0; }
    __syncthreads();
    const int g = blockIdx.x;
    const int e0 = g * CHUNK;
    for (int i = threadIdx.x; i < CHUNK; i += 256) {
        atomicAdd(&hd[dst[e0 + i] >> 9], 1);
        atomicAdd(&hs[src[e0 + i] >> 9], 1);
    }
    __syncthreads();
    for (int i = threadIdx.x; i < BBUK; i += 256) {
        counts_d[i * GBIN + g] = hd[i];
        counts_s[i * GBIN + g] = hs[i];
    }
}

// ---------------- fast CSR 2: fused exclusive scan of both counts arrays ----------------
// counts_d and counts_s are contiguous (2 * BBUK*GBIN ints); per-half scans.
__global__ void k_cs_a(const int* __restrict__ counts, int* __restrict__ csum) {
    __shared__ int s[256];
    int i = blockIdx.x * 256 + threadIdx.x;
    s[threadIdx.x] = counts[i];
    __syncthreads();
    for (int off = 128; off > 0; off >>= 1) {
        if (threadIdx.x < off) s[threadIdx.x] += s[threadIdx.x + off];
        __syncthreads();
    }
    if (threadIdx.x == 0) csum[blockIdx.x] = s[0];
}

__global__ void k_cs_b2(const int* __restrict__ csum, int* __restrict__ coff) {
    __shared__ int s[512];
    int t = threadIdx.x;
    int half = t >> 8, j = t & 255;
    s[t] = (j < NCB) ? csum[half * NCB + j] : 0;
    __syncthreads();
    for (int off = 1; off < 256; off <<= 1) {
        int v = (j >= off) ? s[t - off] : 0;
        __syncthreads();
        s[t] += v;
        __syncthreads();
    }
    if (j < NCB) coff[half * NCB + j] = (j == 0) ? 0 : s[t - 1];
}

__global__ void k_cs_c(int* __restrict__ counts, const int* __restrict__ coff) {
    __shared__ int s[256];
    int t = threadIdx.x;
    int i = blockIdx.x * 256 + t;
    int v = counts[i];
    s[t] = v;
    __syncthreads();
    for (int off = 1; off < 256; off <<= 1) {
        int u = (t >= off) ? s[t - off] : 0;
        __syncthreads();
        s[t] += u;
        __syncthreads();
    }
    counts[i] = s[t] - v + coff[blockIdx.x];
}

// ---------------- fast CSR 3: private-slice binning of dst-edges AND src-residues ----------------
__global__ __launch_bounds__(256) void k_binscatter2(const int* __restrict__ src,
                                                     const int* __restrict__ dst,
                                                     const int* __restrict__ counts_d,
                                                     const int* __restrict__ counts_s,
                                                     unsigned int* __restrict__ packed,
                                                     unsigned short* __restrict__ packed2) {
    __shared__ int curd[BBUK], curs[BBUK];
    const int g = blockIdx.x;
    for (int i = threadIdx.x; i < BBUK; i += 256) {
        curd[i] = counts_d[i * GBIN + g];
        curs[i] = counts_s[i * GBIN + g];
    }
    __syncthreads();
    const int e0 = g * CHUNK;
    for (int i = threadIdx.x; i < CHUNK; i += 256) {
        int s = src[e0 + i], d = dst[e0 + i];
        int pd = atomicAdd(&curd[d >> 9], 1);
        packed[pd] = ((unsigned)s << 9) | (unsigned)(d & 511);
        int ps = atomicAdd(&curs[s >> 9], 1);
        packed2[ps] = (unsigned short)(s & 511);
    }
}

// ---------------- fast CSR 4: per-bucket LDS degree histograms (no global atomics) ----------------
__global__ __launch_bounds__(256) void k_bdeg_in(const int* __restrict__ counts_d,
                                                 const unsigned int* __restrict__ packed,
                                                 int* __restrict__ deg_in) {
    __shared__ int h[512];
    const int b = blockIdx.x;
    const int n0 = b << 9;
    const int nlim = (NN - n0 < 512) ? (NN - n0) : 512;
    for (int j = threadIdx.x; j < 512; j += 256) h[j] = 0;
    __syncthreads();
    const int beg = counts_d[b * GBIN];
    const int end = (b + 1 < BBUK) ? counts_d[(b + 1) * GBIN] : NE;
    for (int i = beg + threadIdx.x; i < end; i += 256)
        atomicAdd(&h[packed[i] & 511u], 1);
    __syncthreads();
    for (int j = threadIdx.x; j < nlim; j += 256) deg_in[n0 + j] = h[j];
}

__global__ __launch_bounds__(256) void k_bdeg_out(const int* __restrict__ counts_s,
                                                  const unsigned short* __restrict__ packed2,
                                                  int* __restrict__ deg_out) {
    __shared__ int h[512];
    const int b = blockIdx.x;
    const int n0 = b << 9;
    const int nlim = (NN - n0 < 512) ? (NN - n0) : 512;
    for (int j = threadIdx.x; j < 512; j += 256) h[j] = 0;
    __syncthreads();
    const int beg = counts_s[b * GBIN];
    const int end = (b + 1 < BBUK) ? counts_s[(b + 1) * GBIN] : NE;
    for (int i = beg + threadIdx.x; i < end; i += 256)
        atomicAdd(&h[packed2[i] & 511u], 1);
    __syncthreads();
    for (int j = threadIdx.x; j < nlim; j += 256) deg_out[n0 + j] = h[j];
}

// ---------------- node-level scan -> row_off, cursors, norms ----------------
__global__ void k_scan_a(const int* __restrict__ deg_in, int* __restrict__ bsum) {
    __shared__ int s[256];
    int i = blockIdx.x * 256 + threadIdx.x;
    s[threadIdx.x] = (i < NN) ? deg_in[i] : 0;
    __syncthreads();
    for (int off = 128; off > 0; off >>= 1) {
        if (threadIdx.x < off) s[threadIdx.x] += s[threadIdx.x + off];
        __syncthreads();
    }
    if (threadIdx.x == 0) bsum[blockIdx.x] = s[0];
}

__global__ void k_scan_b(const int* __restrict__ bsum, int* __restrict__ boff) {
    __shared__ int s[512];
    int t = threadIdx.x;
    s[t] = (t < NB1) ? bsum[t] : 0;
    __syncthreads();
    for (int off = 1; off < 512; off <<= 1) {
        int v = (t >= off) ? s[t - off] : 0;
        __syncthreads();
        s[t] += v;
        __syncthreads();
    }
    if (t < NB1) boff[t] = (t == 0) ? 0 : s[t - 1];
}

__global__ void k_scan_c(const int* __restrict__ deg_in, const int* __restrict__ deg_out,
                         const int* __restrict__ boff, int* __restrict__ row_off,
                         int* __restrict__ cursor, float* __restrict__ nsrc,
                         float* __restrict__ ndst) {
    __shared__ int s[256];
    int t = threadIdx.x;
    int i = blockIdx.x * 256 + t;
    int d = (i < NN) ? deg_in[i] : 0;
    s[t] = d;
    __syncthreads();
    for (int off = 1; off < 256; off <<= 1) {
        int v = (t >= off) ? s[t - off] : 0;
        __syncthreads();
        s[t] += v;
        __syncthreads();
    }
    int excl = s[t] - d + boff[blockIdx.x];
    if (i < NN) {
        row_off[i] = excl;
        cursor[i]  = excl;
        ndst[i] = rsqrtf(fmaxf((float)d, 1.0f));
        nsrc[i] = rsqrtf(fmaxf((float)deg_out[i], 1.0f));
        if (i == NN - 1) row_off[NN] = excl + d;
    }
}

// ---------------- fast CSR 5: within-bucket scatter via LDS cursors ----------------
__global__ __launch_bounds__(256) void k_bucketC512(const int* __restrict__ row_off,
                                                    const unsigned int* __restrict__ packed,
                                                    int* __restrict__ srcs_sorted) {
    __shared__ int lcur[512];
    const int n0 = blockIdx.x << 9;
    const int nlim = (NN - n0 < 512) ? (NN - n0) : 512;
    for (int j = threadIdx.x; j < 512; j += 256)
        lcur[j] = (j < nlim) ? row_off[n0 + j] : 0;
    __syncthreads();
    const int beg = row_off[n0];
    const int end = row_off[n0 + nlim];
    for (int i = beg + threadIdx.x; i < end; i += 256) {
        unsigned v = packed[i];
        int p = atomicAdd(&lcur[v & 511u], 1);
        srcs_sorted[p] = (int)(v >> 9);
    }
}

// ---------------- layer 1 GEMM: h1 = bf16((x @ W1) * nsrc) ----------------
__global__ __launch_bounds__(256) void k_gemm1(
    const void* __restrict__ x, const void* __restrict__ W1,
    const float* __restrict__ nsrc, unsigned short* __restrict__ h1,
    const int* __restrict__ mode)
{
    __shared__ float Ws[NF][NH];     // 32 KB
    __shared__ float xs[4][4][NF];   // 8 KB
    const bool f32 = (mode[0] != 0);
    const int tid = threadIdx.x;
    for (int i = tid; i < NF * NH; i += 256) Ws[i / NH][i % NH] = ldf(W1, i, f32);
    __syncthreads();

    const int wave = tid >> 6, lane = tid & 63;
    const int r  = lane >> 4;
    const int k0 = (lane & 15) * 8;

    for (int g = blockIdx.x; g < NN / 16; g += gridDim.x) {
        const int base = g * 16 + wave * 4;
        __syncthreads();
        if (f32) {
            const float4* xp = (const float4*)((const float*)x + (size_t)base * NF);
            float4 v0 = xp[lane * 2], v1 = xp[lane * 2 + 1];
            float* dp = &xs[wave][r][k0];
            dp[0]=v0.x; dp[1]=v0.y; dp[2]=v0.z; dp[3]=v0.w;
            dp[4]=v1.x; dp[5]=v1.y; dp[6]=v1.z; dp[7]=v1.w;
        } else {
            const uint4* xp = (const uint4*)((const unsigned short*)x + (size_t)base * NF);
            uint4 v = xp[lane];
            unsigned short us[8];
            *(uint4*)us = v;
            float* dp = &xs[wave][r][k0];
            #pragma unroll
            for (int j = 0; j < 8; ++j) dp[j] = us2f(us[j]);
        }
        __syncthreads();

        float a0 = 0.f, a1 = 0.f, a2 = 0.f, a3 = 0.f;
        #pragma unroll 4
        for (int k = 0; k < NF; k += 4) {
            float4 x0 = *(const float4*)&xs[wave][0][k];
            float4 x1 = *(const float4*)&xs[wave][1][k];
            float4 x2 = *(const float4*)&xs[wave][2][k];
            float4 x3 = *(const float4*)&xs[wave][3][k];
            float w0 = Ws[k][lane], w1 = Ws[k+1][lane];
            float w2 = Ws[k+2][lane], w3 = Ws[k+3][lane];
            a0 = fmaf(x0.x,w0,fmaf(x0.y,w1,fmaf(x0.z,w2,fmaf(x0.w,w3,a0))));
            a1 = fmaf(x1.x,w0,fmaf(x1.y,w1,fmaf(x1.z,w2,fmaf(x1.w,w3,a1))));
            a2 = fmaf(x2.x,w0,fmaf(x2.y,w1,fmaf(x2.z,w2,fmaf(x2.w,w3,a2))));
            a3 = fmaf(x3.x,w0,fmaf(x3.y,w1,fmaf(x3.z,w2,fmaf(x3.w,w3,a3))));
        }
        h1[(size_t)(base+0)*NH+lane] = f2us_rn(a0 * nsrc[base+0]);
        h1[(size_t)(base+1)*NH+lane] = f2us_rn(a1 * nsrc[base+1]);
        h1[(size_t)(base+2)*NH+lane] = f2us_rn(a2 * nsrc[base+2]);
        h1[(size_t)(base+3)*NH+lane] = f2us_rn(a3 * nsrc[base+3]);
    }
}

// ---------------- fused layer-1 aggregation + relu + W2 GEMM ----------------
__global__ __launch_bounds__(256) void k_agg1csr(
    const int* __restrict__ row_off, const int* __restrict__ srcs,
    const unsigned short* __restrict__ h1, const float* __restrict__ ndst,
    const float* __restrict__ nsrc, const void* __restrict__ b1,
    const void* __restrict__ W2, const int* __restrict__ mode,
    unsigned short* __restrict__ h2)
{
    const bool f32 = (mode[0] != 0);
    const int lane = threadIdx.x & 63;
    const int q  = lane >> 4;    // edge slot / column subset
    const int li = lane & 15;    // feature quad: feats 4li..4li+3

    const float bias0 = ldf(b1, 4*li+0, f32), bias1 = ldf(b1, 4*li+1, f32);
    const float bias2 = ldf(b1, 4*li+2, f32), bias3 = ldf(b1, 4*li+3, f32);
    float w2[4][4];
    #pragma unroll
    for (int j = 0; j < 4; ++j)
        #pragma unroll
        for (int m = 0; m < 4; ++m)
            w2[j][m] = ldf(W2, (size_t)(4*li+j)*NC + (q + 4*m), f32);

    const int wid = (blockIdx.x * blockDim.x + threadIdx.x) >> 6;
    const int nw  = (gridDim.x * blockDim.x) >> 6;

    for (int row = wid; row < NN; row += nw) {
        const int beg = row_off[row], end = row_off[row + 1];
        float ax = 0.f, ay = 0.f, az = 0.f, aw = 0.f;
        float bx = 0.f, by = 0.f, bz = 0.f, bw = 0.f;
        int i = beg + q;
        int s0 = (i     < end) ? srcs[i]     : 0;
        int s1 = (i + 4 < end) ? srcs[i + 4] : 0;
        while (i + 4 < end) {
            uint2 v0 = *(const uint2*)(h1 + (size_t)s0 * NH + 4*li);
            uint2 v1 = *(const uint2*)(h1 + (size_t)s1 * NH + 4*li);
            const int inext = i + 8;
            s0 = (inext     < end) ? srcs[inext]     : 0;
            s1 = (inext + 4 < end) ? srcs[inext + 4] : 0;
            ax += us2f((unsigned short)(v0.x & 0xFFFF));
            ay += us2f((unsigned short)(v0.x >> 16));
            az += us2f((unsigned short)(v0.y & 0xFFFF));
            aw += us2f((unsigned short)(v0.y >> 16));
            bx += us2f((unsigned short)(v1.x & 0xFFFF));
            by += us2f((unsigned short)(v1.x >> 16));
            bz += us2f((unsigned short)(v1.y & 0xFFFF));
            bw += us2f((unsigned short)(v1.y >> 16));
            i = inext;
        }
        if (i < end) {
            uint2 v0 = *(const uint2*)(h1 + (size_t)s0 * NH + 4*li);
            ax += us2f((unsigned short)(v0.x & 0xFFFF));
            ay += us2f((unsigned short)(v0.x >> 16));
            az += us2f((unsigned short)(v0.y & 0xFFFF));
            aw += us2f((unsigned short)(v0.y >> 16));
        }
        ax += bx; ay += by; az += bz; aw += bw;
        ax += __shfl_xor(ax, 16); ay += __shfl_xor(ay, 16);
        az += __shfl_xor(az, 16); aw += __shfl_xor(aw, 16);
        ax += __shfl_xor(ax, 32); ay += __shfl_xor(ay, 32);
        az += __shfl_xor(az, 32); aw += __shfl_xor(aw, 32);

        const float nd = ndst[row];
        const float t0 = fmaxf(fmaf(ax, nd, bias0), 0.f);
        const float t1 = fmaxf(fmaf(ay, nd, bias1), 0.f);
        const float t2 = fmaxf(fmaf(az, nd, bias2), 0.f);
        const float t3 = fmaxf(fmaf(aw, nd, bias3), 0.f);

        float p0 = fmaf(t0,w2[0][0],fmaf(t1,w2[1][0],fmaf(t2,w2[2][0],t3*w2[3][0])));
        float p1 = fmaf(t0,w2[0][1],fmaf(t1,w2[1][1],fmaf(t2,w2[2][1],t3*w2[3][1])));
        float p2 = fmaf(t0,w2[0][2],fmaf(t1,w2[1][2],fmaf(t2,w2[2][2],t3*w2[3][2])));
        float p3 = fmaf(t0,w2[0][3],fmaf(t1,w2[1][3],fmaf(t2,w2[2][3],t3*w2[3][3])));
        #pragma unroll
        for (int off = 1; off <= 8; off <<= 1) {
            p0 += __shfl_xor(p0, off);
            p1 += __shfl_xor(p1, off);
            p2 += __shfl_xor(p2, off);
            p3 += __shfl_xor(p3, off);
        }
        if (li < 4) {
            float v = (li == 0) ? p0 : (li == 1) ? p1 : (li == 2) ? p2 : p3;
            h2[(size_t)row * NC + q + 4*li] = f2us_rn(v * nsrc[row]);
        }
    }
}

// ---------------- fused layer-2 aggregation + bias + log_softmax ----------------
__global__ __launch_bounds__(256) void k_out(
    const int* __restrict__ row_off, const int* __restrict__ srcs,
    const unsigned short* __restrict__ h2, const float* __restrict__ ndst,
    const void* __restrict__ b2, const int* __restrict__ mode,
    void* __restrict__ out)
{
    const bool f32 = (mode[0] != 0);
    const int lane = threadIdx.x & 63;
    const int q  = lane >> 4;
    const int li = lane & 15;
    const float b2v = ldf(b2, li, f32);

    const int wid = (blockIdx.x * blockDim.x + threadIdx.x) >> 6;
    const int nw  = (gridDim.x * blockDim.x) >> 6;

    for (int r = wid; r < NN; r += nw) {
        const int beg = row_off[r], end = row_off[r + 1];
        float a = 0.f, b = 0.f;
        int i = beg + q;
        int s0 = (i     < end) ? srcs[i]     : 0;
        int s1 = (i + 4 < end) ? srcs[i + 4] : 0;
        while (i + 4 < end) {
            float va = us2f(h2[(size_t)s0 * NC + li]);
            float vb = us2f(h2[(size_t)s1 * NC + li]);
            const int inext = i + 8;
            s0 = (inext     < end) ? srcs[inext]     : 0;
            s1 = (inext + 4 < end) ? srcs[inext + 4] : 0;
            a += va; b += vb;
            i = inext;
        }
        if (i < end) a += us2f(h2[(size_t)s0 * NC + li]);
        a += b;
        a += __shfl_xor(a, 16);
        a += __shfl_xor(a, 32);
        float v = fmaf(a, ndst[r], b2v);
        float m = v;
        #pragma unroll
        for (int off = 8; off >= 1; off >>= 1) m = fmaxf(m, __shfl_xor(m, off));
        float ex = __expf(v - m);
        float sm = ex;
        #pragma unroll
        for (int off = 8; off >= 1; off >>= 1) sm += __shfl_xor(sm, off);
        float res = v - m - __logf(sm);
        if (lane < 16) {
            if (f32) ((float*)out)[(size_t)r * NC + li] = res;
            else ((__hip_bfloat16*)out)[(size_t)r * NC + li] = __float2bfloat16(res);
        }
    }
}

extern "C" void kernel_launch(void* const* d_in, const int* in_sizes, int n_in,
                              void* d_out, int out_size, void* d_ws, size_t ws_size,
                              hipStream_t stream) {
    const void* x  = d_in[0];
    const int* src = (const int*)d_in[1];
    const int* dst = (const int*)d_in[2];
    const void* W1 = d_in[3];
    const void* b1 = d_in[4];
    const void* W2 = d_in[5];
    const void* b2 = d_in[6];

    // ---- workspace layout ----
    char* ws = (char*)d_ws;
    const size_t O_MODE = 0;                     // 1 KB
    const size_t O_CNT  = 1024;                  // counts_d + counts_s, 2*BBUK*GBIN*4 = 401408
    const size_t O_CS   = O_CNT  + 401408;       // csum 2048 + coff 2048
    const size_t O_DEG  = O_CS   + 4096;         // 800000
    const size_t O_NSRC = O_DEG  + 800000;
    const size_t O_NDST = O_NSRC + 400000;
    const size_t O_ROW  = O_NDST + 400000;       // (NN+1)*4 padded
    const size_t O_CUR  = O_ROW  + 400128;       // fallback per-node cursors
    const size_t O_BS   = O_CUR  + 400128;       // bsum 2048 + boff 2048
    const size_t O_SRCS = O_BS   + 4096;         // NE*4
    const size_t O_H2   = O_SRCS + 6400000;      // NN*NC*2 bf16
    const size_t O_H1   = O_H2   + 3200000;      // NN*NH*2 bf16 = 12800000
    // packed (NE*4) + packed2 (NE*2) alias into the h1 region: both are
    // dead before k_gemm1 writes h1 (bucketC512 / bdeg_out consume them).
    const size_t NEED = O_H1 + 12800000;         // ~25.2 MB
    const bool fast_csr = ws_size >= NEED;       // fallback: atomic deg+scatter

    int*   mode     = (int*)(ws + O_MODE);
    int*   counts_d = (int*)(ws + O_CNT);
    int*   counts_s = counts_d + BBUK * GBIN;
    int*   csum     = (int*)(ws + O_CS);
    int*   coff     = (int*)(ws + O_CS + 2048);
    int*   deg_out  = (int*)(ws + O_DEG);
    int*   deg_in   = deg_out + NN;
    float* nsrc     = (float*)(ws + O_NSRC);
    float* ndst     = (float*)(ws + O_NDST);
    int*   row_off  = (int*)(ws + O_ROW);
    int*   cursor   = (int*)(ws + O_CUR);
    int*   bsum     = (int*)(ws + O_BS);
    int*   boff     = (int*)(ws + O_BS + 2048);
    int*   srcs_s   = (int*)(ws + O_SRCS);
    unsigned short* h2 = (unsigned short*)(ws + O_H2);
    unsigned short* h1 = (unsigned short*)(ws + O_H1);
    unsigned int*   packed  = (unsigned int*)(ws + O_H1);
    unsigned short* packed2 = (unsigned short*)(ws + O_H1 + 6400000);

    k_sniff<<<1, 256, 0, stream>>>((const unsigned short*)x, mode);
    if (fast_csr) {
        // no global atomics anywhere on this path
        k_hist2<<<GBIN, 256, 0, stream>>>(src, dst, counts_d, counts_s);
        k_cs_a<<<2 * NCB, 256, 0, stream>>>(counts_d, csum);
        k_cs_b2<<<1, 512, 0, stream>>>(csum, coff);
        k_cs_c<<<2 * NCB, 256, 0, stream>>>(counts_d, coff);
        k_binscatter2<<<GBIN, 256, 0, stream>>>(src, dst, counts_d, counts_s, packed, packed2);
        k_bdeg_in<<<BBUK, 256, 0, stream>>>(counts_d, packed, deg_in);
        k_bdeg_out<<<BBUK, 256, 0, stream>>>(counts_s, packed2, deg_out);
        k_scan_a<<<NB1, 256, 0, stream>>>(deg_in, bsum);
        k_scan_b<<<1, 512, 0, stream>>>(bsum, boff);
        k_scan_c<<<NB1, 256, 0, stream>>>(deg_in, deg_out, boff, row_off, cursor, nsrc, ndst);
        k_bucketC512<<<BBUK, 256, 0, stream>>>(row_off, packed, srcs_s);
    } else {
        hipMemsetAsync(deg_out, 0, 2 * (size_t)NN * sizeof(int), stream);
        k_deg<<<(NE / 4 + 255) / 256, 256, 0, stream>>>((const int4*)src, (const int4*)dst, deg_out, deg_in);
        k_scan_a<<<NB1, 256, 0, stream>>>(deg_in, bsum);
        k_scan_b<<<1, 512, 0, stream>>>(bsum, boff);
        k_scan_c<<<NB1, 256, 0, stream>>>(deg_in, deg_out, boff, row_off, cursor, nsrc, ndst);
        k_scatter<<<(NE + 255) / 256, 256, 0, stream>>>(src, dst, cursor, srcs_s);
    }
    k_gemm1<<<2048, 256, 0, stream>>>(x, W1, nsrc, h1, mode);
    k_agg1csr<<<2048, 256, 0, stream>>>(row_off, srcs_s, h1, ndst, nsrc, b1, W2, mode, h2);
    k_out<<<2048, 256, 0, stream>>>(row_off, srcs_s, h2, ndst, b2, mode, d_out);
}